// Round 1
// baseline (26.845 us; speedup 1.0000x reference)
//
#include <hip/hip_runtime.h>
#include <math.h>

#define NBINS 256
#define BINW (1.0f / 256.0f)

// One block per batch row. 256 threads:
//  - thread j computes knot j: x_abs = clip(center_j + tanh(p0)*0.5*bw, 0, 1), t = p1
//  - knots staged in LDS as float2 {x_abs, t}
//  - then grid of float4 query loads; O(1) segment lookup per element.
__global__ __launch_bounds__(256) void pwl_kernel(
    const float* __restrict__ inp,   // [B, 256, 2] interleaved (p0, p1)
    const float* __restrict__ x,     // [B, nq]
    float* __restrict__ out,         // [B, nq]
    int nq)
{
    __shared__ float2 s_xt[NBINS];   // {x_abs, t}

    const int b   = blockIdx.x;
    const int tid = threadIdx.x;

    // ---- stage knots ----
    float2 p = ((const float2*)inp)[(size_t)b * NBINS + tid];
    float center = ((float)tid + 0.5f) * BINW;
    float xa = center + tanhf(p.x) * (0.5f * BINW);
    xa = fminf(fmaxf(xa, 0.0f), 1.0f);
    s_xt[tid] = make_float2(xa, p.y);
    __syncthreads();

    // ---- evaluate queries ----
    const float4* xrow = (const float4*)(x + (size_t)b * nq);
    float4*       orow = (float4*)(out + (size_t)b * nq);
    const int nvec = nq >> 2;

    for (int i = tid; i < nvec; i += 256) {
        float4 q = xrow[i];
        float4 r;
        float* qv = (float*)&q;
        float* rv = (float*)&r;
#pragma unroll
        for (int c = 0; c < 4; ++c) {
            float xi = qv[c];
            // exact: xi*256 is a power-of-2 multiply; xi in [0,1)
            int k = (int)(xi * 256.0f);
            k = min(max(k, 0), NBINS - 1);

            float2 pk = s_xt[k];
            // bracketing partner knot: k+1 if xi right of knot k, else k-1.
            int o = (xi >= pk.x) ? (k + 1) : (k - 1);
            // edge fixes double as extrapolation (first/last segment slope):
            if (o < 0)        o = 1;            // k==0, xi < x_abs[0]
            if (o > NBINS-1)  o = NBINS - 2;    // k==255, xi >= x_abs[255]

            float2 po = s_xt[o];
            float2 lo = (o > k) ? pk : po;
            float2 hi = (o > k) ? po : pk;

            rv[c] = lo.y + (xi - lo.x) * ((hi.y - lo.y) / (hi.x - lo.x));
        }
        orow[i] = r;
    }
}

extern "C" void kernel_launch(void* const* d_in, const int* in_sizes, int n_in,
                              void* d_out, int out_size, void* d_ws, size_t ws_size,
                              hipStream_t stream)
{
    const float* inp = (const float*)d_in[0];   // [B, 256, 2]
    const float* x   = (const float*)d_in[1];   // [B, nq]
    float*       out = (float*)d_out;           // [B, nq]

    const int B  = in_sizes[0] / (2 * NBINS);
    const int nq = in_sizes[1] / B;             // divisible by 4 (4096)

    pwl_kernel<<<B, 256, 0, stream>>>(inp, x, out, nq);
}